// Round 9
// baseline (113.911 us; speedup 1.0000x reference)
//
#include <hip/hip_runtime.h>
#include <hip/hip_bf16.h>

typedef __bf16 bf16;
typedef __attribute__((ext_vector_type(4))) __bf16 bf16x4;
typedef __attribute__((ext_vector_type(8))) __bf16 bf16x8;
typedef __attribute__((ext_vector_type(4))) float f32x4;

#define GLD_LDS16(g, l)                                              \
  __builtin_amdgcn_global_load_lds(                                  \
      (const __attribute__((address_space(1))) void*)(g),            \
      (__attribute__((address_space(3))) void*)(l), 16, 0, 0)

// ---- prep: z<3 -> transpose+cast W[z] (K,N)->(N,K) bf16; z==3 -> cast x ----
__global__ void prep_kernel(const float* __restrict__ x,
                            const float* __restrict__ Wq,
                            const float* __restrict__ Wk,
                            const float* __restrict__ Wv,
                            bf16* __restrict__ xb, bf16* __restrict__ Wt) {
  __shared__ float tile[32][33];
  const int z = blockIdx.z;
  const int t = threadIdx.x;
  if (z < 3) {
    const float* W = (z == 0) ? Wq : ((z == 1) ? Wk : Wv);
    bf16* out = Wt + (size_t)z * 1024 * 1024;
    const int k0 = blockIdx.x * 32, n0 = blockIdx.y * 32;
    const int r = t >> 3, c = (t & 7) * 4;
    float4 v = *reinterpret_cast<const float4*>(&W[(size_t)(k0 + r) * 1024 + n0 + c]);
    tile[r][c + 0] = v.x; tile[r][c + 1] = v.y;
    tile[r][c + 2] = v.z; tile[r][c + 3] = v.w;
    __syncthreads();
    bf16x4 o;
    o[0] = (bf16)tile[c + 0][r]; o[1] = (bf16)tile[c + 1][r];
    o[2] = (bf16)tile[c + 2][r]; o[3] = (bf16)tile[c + 3][r];
    *reinterpret_cast<bf16x4*>(&out[(size_t)(n0 + r) * 1024 + k0 + c]) = o;
  } else {
    const int tid = (blockIdx.y * 32 + blockIdx.x) * 256 + t;
#pragma unroll
    for (int i = 0; i < 8; ++i) {
      const int idx = tid + i * 262144;
      float4 v = reinterpret_cast<const float4*>(x)[idx];
      bf16x4 o;
      o[0] = (bf16)v.x; o[1] = (bf16)v.y; o[2] = (bf16)v.z; o[3] = (bf16)v.w;
      reinterpret_cast<bf16x4*>(xb)[idx] = o;
    }
  }
}

// --------- fused QKV GEMM: C[8192][3072] = x @ Wt^T + bias ----------------
// BM=256 BN=384 BK=32, grid 32x8 = 256 blocks (exactly 1 round, no tail).
// 8 waves 2Mx4N, per-wave 128x96 (FLOP/LDS-byte = 55 vs 32 before).
// 3-deep literal-index LDS ring (120 KB), counted vmcnt(5), granule-XOR
// swizzle (granule ^= (row>>1)&3 on 64-B rows), loose R7-style schedule.
__global__ __launch_bounds__(512, 2) void qkv_gemm_kernel(
    const bf16* __restrict__ xb, const bf16* __restrict__ Wt,
    const float* __restrict__ bq, const float* __restrict__ bk,
    const float* __restrict__ bv, bf16* __restrict__ QKV) {
  __shared__ bf16 ldsA[3][256 * 32];  // 3 x 16 KB
  __shared__ bf16 ldsB[3][384 * 32];  // 3 x 24 KB

  const int m0 = blockIdx.x * 256;   // x = m so XCD round-robin shares B in L2
  const int n0g = blockIdx.y * 384;

  const int t = threadIdx.x;
  const int lane = t & 63, wid = t >> 6;
  const int wr = wid >> 2, wc = wid & 3;   // 2M x 4N waves -> 128x96 each
  const int l15 = lane & 15, kg = lane >> 4;

  // staging: chunk = 128 rows x 32 cols (8 KB), 512 thr x 16 B
  // dest linear: elem = chunk*4096 + t*8 ; src granule pre-swizzled
  const int srow = t >> 2;                         // 0..127 within chunk
  const int sgl = ((t & 3) ^ ((t >> 3) & 3)) * 8;  // swizzled source col (elems)

  auto stageA = [&](int c, int kt, int buf) {
    GLD_LDS16(xb + (size_t)(m0 + c * 128 + srow) * 1024 + kt + sgl,
              &ldsA[buf][c * 4096 + t * 8]);
  };
  auto stageB = [&](int c, int kt, int buf) {
    GLD_LDS16(Wt + (size_t)(n0g + c * 128 + srow) * 1024 + kt + sgl,
              &ldsB[buf][c * 4096 + t * 8]);
  };
  // fragment reads: row*32 elems + swizzled granule (8 elems each)
  auto readA = [&](const bf16* Ab, int mi) {
    const int row = wr * 128 + mi * 16 + l15;
    return *reinterpret_cast<const bf16x8*>(
        Ab + row * 32 + ((kg ^ ((row >> 1) & 3)) << 3));
  };
  auto readB = [&](const bf16* Bb, int ni) {
    const int row = wc * 96 + ni * 16 + l15;
    return *reinterpret_cast<const bf16x8*>(
        Bb + row * 32 + ((kg ^ ((row >> 1) & 3)) << 3));
  };

  f32x4 acc[8][6];
#pragma unroll
  for (int i = 0; i < 8; ++i)
#pragma unroll
    for (int j = 0; j < 6; ++j) { f32x4 zz = {0.f, 0.f, 0.f, 0.f}; acc[i][j] = zz; }

  // prologue: tile 0 -> buf0, tile 1 -> buf1 (10 loads in flight)
  stageA(0, 0, 0); stageA(1, 0, 0);
  stageB(0, 0, 0); stageB(1, 0, 0); stageB(2, 0, 0);
  stageA(0, 32, 1); stageA(1, 32, 1);
  stageB(0, 32, 1); stageB(1, 32, 1); stageB(2, 32, 1);

// One K-tile: boundary wait+barrier; 6 B-frag reads; 5 stage DMAs (tile+2);
// mi-loop {A-frag read; 6 MFMA} free-running (compiler lgkm-interleaves).
#define KTILE(RB, WB, kt, DO_STAGE, LAST)                                      \
  {                                                                            \
    if (LAST) { asm volatile("s_waitcnt vmcnt(0)" ::: "memory"); }             \
    else      { asm volatile("s_waitcnt vmcnt(5)" ::: "memory"); }             \
    __builtin_amdgcn_s_barrier();                                              \
    bf16x8 bfr[6];                                                             \
    _Pragma("unroll")                                                          \
    for (int ni = 0; ni < 6; ++ni) bfr[ni] = readB(&ldsB[RB][0], ni);          \
    __builtin_amdgcn_sched_barrier(0);                                         \
    if (DO_STAGE) {                                                            \
      stageA(0, (kt) + 64, WB); stageA(1, (kt) + 64, WB);                      \
      stageB(0, (kt) + 64, WB); stageB(1, (kt) + 64, WB);                      \
      stageB(2, (kt) + 64, WB);                                                \
    }                                                                          \
    __builtin_amdgcn_s_setprio(1);                                             \
    _Pragma("unroll")                                                          \
    for (int mi = 0; mi < 8; ++mi) {                                           \
      bf16x8 af = readA(&ldsA[RB][0], mi);                                     \
      _Pragma("unroll")                                                        \
      for (int ni = 0; ni < 6; ++ni)                                           \
        acc[mi][ni] = __builtin_amdgcn_mfma_f32_16x16x32_bf16(                 \
            af, bfr[ni], acc[mi][ni], 0, 0, 0);                                \
    }                                                                          \
    __builtin_amdgcn_s_setprio(0);                                             \
  }

  // tiles 0..29 in groups of 3 (bufs 0,1,2); stage target = tile+2
  for (int g = 0; g < 10; ++g) {
    const int kb = g * 96;
    KTILE(0, 2, kb,      true, false);
    KTILE(1, 0, kb + 32, true, false);
    KTILE(2, 1, kb + 64, true, false);
  }
  // tail: tiles 30 (buf 0), 31 (buf 1); no staging
  KTILE(0, 2, 960, false, false);
  KTILE(1, 0, 992, false, true);
#undef KTILE

  // epilogue: C/D layout col = lane&15, row = (lane>>4)*4 + reg  [m89/m91]
  const int rowb = kg * 4;
#pragma unroll
  for (int ni = 0; ni < 6; ++ni) {
    const int col = n0g + wc * 96 + ni * 16 + l15;        // global col, may
    const int cz = col & 1023;                            // cross q/k/v
    const float bv_ = (col < 1024) ? bq[cz] : ((col < 2048) ? bk[cz] : bv[cz]);
#pragma unroll
    for (int mi = 0; mi < 8; ++mi) {
      const int row = m0 + wr * 128 + mi * 16 + rowb;
#pragma unroll
      for (int j = 0; j < 4; ++j)
        QKV[(size_t)(row + j) * 3072 + col] = (bf16)(acc[mi][ni][j] + bv_);
    }
  }
}

// ------- local attention, window +-2; QKV fused rows [p][3072] ------------
__global__ void local_attn_kernel(const bf16* __restrict__ QKV,
                                  float* __restrict__ out) {
  const int t = threadIdx.x;
  const int lane = t & 63, wid = t >> 6;
  const int p = blockIdx.x * 4 + wid;  // b*2048 + s
  const int s = p & 2047;
  const size_t hoff = (size_t)lane * 16;

  float qf[16];
  {
    const bf16* qp = QKV + (size_t)p * 3072 + hoff;
    bf16x8 q0 = *reinterpret_cast<const bf16x8*>(qp);
    bf16x8 q1 = *reinterpret_cast<const bf16x8*>(qp + 8);
#pragma unroll
    for (int j = 0; j < 8; ++j) { qf[j] = (float)q0[j]; qf[8 + j] = (float)q1[j]; }
  }

  float sc[5];
#pragma unroll
  for (int w = 0; w < 5; ++w) {
    const int sp = s + w - 2;  // wave-uniform
    if (sp < 0 || sp >= 2048) { sc[w] = -__builtin_inff(); continue; }
    const bf16* kp = QKV + (size_t)(p + w - 2) * 3072 + 1024 + hoff;
    bf16x8 k0 = *reinterpret_cast<const bf16x8*>(kp);
    bf16x8 k1 = *reinterpret_cast<const bf16x8*>(kp + 8);
    float d = 0.f;
#pragma unroll
    for (int j = 0; j < 8; ++j) d += qf[j] * (float)k0[j] + qf[8 + j] * (float)k1[j];
#pragma unroll
    for (int off = 32; off >= 1; off >>= 1) d += __shfl_xor(d, off, 64);
    sc[w] = d * (1.0f / 32.0f);  // /sqrt(1024)
  }

  float m = -__builtin_inff();
#pragma unroll
  for (int w = 0; w < 5; ++w) m = fmaxf(m, sc[w]);
  float e[5], sum = 0.f;
#pragma unroll
  for (int w = 0; w < 5; ++w) { e[w] = __expf(sc[w] - m); sum += e[w]; }
  const float inv = 1.0f / sum;

  float of[16];
#pragma unroll
  for (int j = 0; j < 16; ++j) of[j] = 0.f;
#pragma unroll
  for (int w = 0; w < 5; ++w) {
    const int sp = s + w - 2;
    if (sp < 0 || sp >= 2048) continue;
    const float pw = e[w] * inv;
    const bf16* vp = QKV + (size_t)(p + w - 2) * 3072 + 2048 + hoff;
    bf16x8 v0 = *reinterpret_cast<const bf16x8*>(vp);
    bf16x8 v1 = *reinterpret_cast<const bf16x8*>(vp + 8);
#pragma unroll
    for (int j = 0; j < 8; ++j) { of[j] += pw * (float)v0[j]; of[8 + j] += pw * (float)v1[j]; }
  }

  float* op = out + (size_t)p * 1024 + hoff;
#pragma unroll
  for (int j4 = 0; j4 < 4; ++j4) {
    f32x4 o = {of[4 * j4 + 0], of[4 * j4 + 1], of[4 * j4 + 2], of[4 * j4 + 3]};
    *reinterpret_cast<f32x4*>(op + 4 * j4) = o;
  }
}

extern "C" void kernel_launch(void* const* d_in, const int* in_sizes, int n_in,
                              void* d_out, int out_size, void* d_ws,
                              size_t ws_size, hipStream_t stream) {
  const float* x  = (const float*)d_in[0];
  const float* Wq = (const float*)d_in[1];
  const float* bq = (const float*)d_in[2];
  const float* Wk = (const float*)d_in[3];
  const float* bk = (const float*)d_in[4];
  const float* Wv = (const float*)d_in[5];
  const float* bv = (const float*)d_in[6];

  char* ws = (char*)d_ws;
  bf16* xb  = (bf16*)ws;                       // 16 MB: x as bf16
  bf16* Wt  = (bf16*)(ws + (size_t)16777216);  // 6 MB: [3072][1024] W^T bf16
  bf16* QKV = (bf16*)(ws + (size_t)23068672);  // 48 MB: fused [8192][3072]
  float* outf = (float*)d_out;

  prep_kernel<<<dim3(32, 32, 4), 256, 0, stream>>>(x, Wq, Wk, Wv, xb, Wt);
  qkv_gemm_kernel<<<dim3(32, 8), 512, 0, stream>>>(xb, Wt, bq, bk, bv, QKV);
  local_attn_kernel<<<2048, 256, 0, stream>>>(QKV, outf);
}

// Round 11
// 99.676 us; speedup vs baseline: 1.1428x; 1.1428x over previous
//
#include <hip/hip_runtime.h>
#include <hip/hip_bf16.h>

typedef __bf16 bf16;
typedef __attribute__((ext_vector_type(4))) __bf16 bf16x4;
typedef __attribute__((ext_vector_type(8))) __bf16 bf16x8;
typedef __attribute__((ext_vector_type(4))) float f32x4;

#define GLD_LDS16(g, l)                                              \
  __builtin_amdgcn_global_load_lds(                                  \
      (const __attribute__((address_space(1))) void*)(g),            \
      (__attribute__((address_space(3))) void*)(l), 16, 0, 0)

// ---- prep: z<3 -> transpose+cast W[z] (K,N)->(N,K) bf16; z==3 -> cast x ----
__global__ void prep_kernel(const float* __restrict__ x,
                            const float* __restrict__ Wq,
                            const float* __restrict__ Wk,
                            const float* __restrict__ Wv,
                            bf16* __restrict__ xb, bf16* __restrict__ Wt) {
  __shared__ float tile[32][33];
  const int z = blockIdx.z;
  const int t = threadIdx.x;
  if (z < 3) {
    const float* W = (z == 0) ? Wq : ((z == 1) ? Wk : Wv);
    bf16* out = Wt + (size_t)z * 1024 * 1024;
    const int k0 = blockIdx.x * 32, n0 = blockIdx.y * 32;
    const int r = t >> 3, c = (t & 7) * 4;
    float4 v = *reinterpret_cast<const float4*>(&W[(size_t)(k0 + r) * 1024 + n0 + c]);
    tile[r][c + 0] = v.x; tile[r][c + 1] = v.y;
    tile[r][c + 2] = v.z; tile[r][c + 3] = v.w;
    __syncthreads();
    bf16x4 o;
    o[0] = (bf16)tile[c + 0][r]; o[1] = (bf16)tile[c + 1][r];
    o[2] = (bf16)tile[c + 2][r]; o[3] = (bf16)tile[c + 3][r];
    *reinterpret_cast<bf16x4*>(&out[(size_t)(n0 + r) * 1024 + k0 + c]) = o;
  } else {
    const int tid = (blockIdx.y * 32 + blockIdx.x) * 256 + t;
#pragma unroll
    for (int i = 0; i < 8; ++i) {
      const int idx = tid + i * 262144;
      float4 v = reinterpret_cast<const float4*>(x)[idx];
      bf16x4 o;
      o[0] = (bf16)v.x; o[1] = (bf16)v.y; o[2] = (bf16)v.z; o[3] = (bf16)v.w;
      reinterpret_cast<bf16x4*>(xb)[idx] = o;
    }
  }
}

// --------- fused QKV GEMM: C[8192][3072] = x @ Wt^T + bias ----------------
// EXACT round-7 structure (best measured: 60.2 us, MfmaUtil 35.6%):
// BM=256 BN=128 BK=64, 8 waves (4Mx2N, 64x64/wave), 3-deep literal-index
// LDS ring, counted vmcnt(6), XOR swizzle, loose single-phase K-tile,
// grid (24,32) = 768 blocks = 3 staggered rounds (epilogue writes overlap).
__global__ __launch_bounds__(512, 2) void qkv_gemm_kernel(
    const bf16* __restrict__ xb, const bf16* __restrict__ Wt,
    const float* __restrict__ bq, const float* __restrict__ bk,
    const float* __restrict__ bv, bf16* __restrict__ QKV) {
  __shared__ bf16 ldsA[3][256 * 64];  // 96 KB
  __shared__ bf16 ldsB[3][128 * 64];  // 48 KB

  const int n0g = blockIdx.x * 128;
  const int m0 = blockIdx.y * 256;
  const int z = n0g >> 10;
  const float* bias = (z == 0) ? bq : ((z == 1) ? bk : bv);
  const int nloc = n0g & 1023;

  const int t = threadIdx.x;
  const int lane = t & 63, wid = t >> 6;
  const int wr = wid >> 1, wc = wid & 1;
  const int l15 = lane & 15, kg = lane >> 4;

  // staging: chunk = 64 rows x 64 cols (8 KB), 512 thr x 16 B
  const int trow = t >> 3;
  const int cdst = (t & 7) * 8;
  const int csrc = (((t & 7) * 16) ^ ((trow & 7) << 4)) >> 1;  // pre-swizzled src

  auto stageA = [&](int c, int kt, bf16* Ab) {
    GLD_LDS16(xb + (size_t)(m0 + c * 64 + trow) * 1024 + kt + csrc,
              Ab + (c * 64 + trow) * 64 + cdst);
  };
  auto stageB = [&](int c, int kt, bf16* Bb) {
    GLD_LDS16(Wt + (size_t)(n0g + c * 64 + trow) * 1024 + kt + csrc,
              Bb + (c * 64 + trow) * 64 + cdst);
  };
  auto readA = [&](const bf16* Ab, int mi, int ks) {
    const int row = wr * 64 + mi * 16 + l15;
    const int colb = (ks * 64 + kg * 16) ^ ((l15 & 7) << 4);
    return *reinterpret_cast<const bf16x8*>(Ab + row * 64 + (colb >> 1));
  };
  auto readB = [&](const bf16* Bb, int ni, int ks) {
    const int row = wc * 64 + ni * 16 + l15;
    const int colb = (ks * 64 + kg * 16) ^ ((l15 & 7) << 4);
    return *reinterpret_cast<const bf16x8*>(Bb + row * 64 + (colb >> 1));
  };

  f32x4 acc[4][4];
#pragma unroll
  for (int i = 0; i < 4; ++i)
#pragma unroll
    for (int j = 0; j < 4; ++j) { f32x4 zz = {0.f, 0.f, 0.f, 0.f}; acc[i][j] = zz; }

  // prologue: tile 0 -> buf0, tile 1 -> buf1 (12 loads in flight)
#pragma unroll
  for (int c = 0; c < 4; ++c) stageA(c, 0, &ldsA[0][0]);
#pragma unroll
  for (int c = 0; c < 2; ++c) stageB(c, 0, &ldsB[0][0]);
#pragma unroll
  for (int c = 0; c < 4; ++c) stageA(c, 64, &ldsA[1][0]);
#pragma unroll
  for (int c = 0; c < 2; ++c) stageB(c, 64, &ldsB[1][0]);

#define KTILE(RB, WB, kt, DO_STAGE, LAST)                                      \
  {                                                                            \
    if (LAST) { asm volatile("s_waitcnt vmcnt(0)" ::: "memory"); }             \
    else      { asm volatile("s_waitcnt vmcnt(6)" ::: "memory"); }             \
    __builtin_amdgcn_s_barrier();                                              \
    bf16x8 af[4][2], bfr[4][2];                                                \
    _Pragma("unroll")                                                          \
    for (int mi = 0; mi < 4; ++mi)                                             \
      _Pragma("unroll")                                                        \
      for (int ks = 0; ks < 2; ++ks) af[mi][ks] = readA(&ldsA[RB][0], mi, ks); \
    _Pragma("unroll")                                                          \
    for (int ni = 0; ni < 4; ++ni)                                             \
      _Pragma("unroll")                                                        \
      for (int ks = 0; ks < 2; ++ks) bfr[ni][ks] = readB(&ldsB[RB][0], ni, ks);\
    __builtin_amdgcn_sched_barrier(0);                                         \
    if (DO_STAGE) {                                                            \
      stageA(0, (kt) + 128, &ldsA[WB][0]);                                     \
      stageA(1, (kt) + 128, &ldsA[WB][0]);                                     \
      stageA(2, (kt) + 128, &ldsA[WB][0]);                                     \
      stageA(3, (kt) + 128, &ldsA[WB][0]);                                     \
      stageB(0, (kt) + 128, &ldsB[WB][0]);                                     \
      stageB(1, (kt) + 128, &ldsB[WB][0]);                                     \
    }                                                                          \
    __builtin_amdgcn_s_setprio(1);                                             \
    _Pragma("unroll")                                                          \
    for (int mi = 0; mi < 4; ++mi)                                             \
      _Pragma("unroll")                                                        \
      for (int ni = 0; ni < 4; ++ni) {                                         \
        acc[mi][ni] = __builtin_amdgcn_mfma_f32_16x16x32_bf16(                 \
            af[mi][0], bfr[ni][0], acc[mi][ni], 0, 0, 0);                      \
        acc[mi][ni] = __builtin_amdgcn_mfma_f32_16x16x32_bf16(                 \
            af[mi][1], bfr[ni][1], acc[mi][ni], 0, 0, 0);                      \
      }                                                                        \
    __builtin_amdgcn_s_setprio(0);                                             \
  }

  for (int g = 0; g < 4; ++g) {
    const int kb = g * 192;
    KTILE(0, 2, kb,       true, false);
    KTILE(1, 0, kb + 64,  true, false);
    KTILE(2, 1, kb + 128, true, false);
  }
  KTILE(0, 2, 768, true,  false);
  KTILE(1, 0, 832, true,  false);
  KTILE(2, 1, 896, false, false);
  KTILE(0, 2, 960, false, true);
#undef KTILE

  // epilogue: C/D layout col = lane&15, row = (lane>>4)*4 + reg  [m89/m91]
  const int rowb = kg * 4;
#pragma unroll
  for (int ni = 0; ni < 4; ++ni) {
    const int cl = wc * 64 + ni * 16 + l15;
    const float bv_ = bias[nloc + cl];
#pragma unroll
    for (int mi = 0; mi < 4; ++mi) {
      const int row = m0 + wr * 64 + mi * 16 + rowb;
#pragma unroll
      for (int j = 0; j < 4; ++j)
        QKV[(size_t)(row + j) * 3072 + n0g + cl] = (bf16)(acc[mi][ni][j] + bv_);
    }
  }
}

// ------- local attention, window +-2; 2 positions per wave ----------------
// Wave handles p0 (even) and p0+1: K/V rows s0-2..s0+3 loaded once (guarded),
// 10 dots with interleaved shuffle-reduce, dual softmax, shared-V accumulate.
__global__ void local_attn_kernel(const bf16* __restrict__ QKV,
                                  float* __restrict__ out) {
  const int t = threadIdx.x;
  const int lane = t & 63, wid = t >> 6;
  const int p0 = blockIdx.x * 8 + wid * 2;  // even; block = 8 consecutive pos
  const int s0 = p0 & 2047;
  const size_t hoff = (size_t)lane * 16;

  float q0f[16], q1f[16];
  {
    const bf16* qp = QKV + (size_t)p0 * 3072 + hoff;
    bf16x8 a0 = *reinterpret_cast<const bf16x8*>(qp);
    bf16x8 a1 = *reinterpret_cast<const bf16x8*>(qp + 8);
    bf16x8 b0 = *reinterpret_cast<const bf16x8*>(qp + 3072);
    bf16x8 b1 = *reinterpret_cast<const bf16x8*>(qp + 3072 + 8);
#pragma unroll
    for (int j = 0; j < 8; ++j) {
      q0f[j] = (float)a0[j]; q0f[8 + j] = (float)a1[j];
      q1f[j] = (float)b0[j]; q1f[8 + j] = (float)b1[j];
    }
  }

  // K/V rows s0-2 .. s0+3 (6 rows), zero-filled when out of range
  bf16x8 kr[6][2], vr[6][2];
  bool val[6];
#pragma unroll
  for (int r = 0; r < 6; ++r) {
    const int sr = s0 - 2 + r;
    val[r] = (sr >= 0) && (sr < 2048);
    if (val[r]) {
      const bf16* kp = QKV + (size_t)(p0 - 2 + r) * 3072 + 1024 + hoff;
      kr[r][0] = *reinterpret_cast<const bf16x8*>(kp);
      kr[r][1] = *reinterpret_cast<const bf16x8*>(kp + 8);
      vr[r][0] = *reinterpret_cast<const bf16x8*>(kp + 1024);
      vr[r][1] = *reinterpret_cast<const bf16x8*>(kp + 1024 + 8);
    } else {
      bf16x8 zz;
#pragma unroll
      for (int j = 0; j < 8; ++j) zz[j] = (bf16)0.f;
      kr[r][0] = zz; kr[r][1] = zz; vr[r][0] = zz; vr[r][1] = zz;
    }
  }

  // 10 dots: q0 x rows 0..4, q1 x rows 1..5
  float d0[5], d1[5];
#pragma unroll
  for (int w = 0; w < 5; ++w) {
    float a = 0.f, b = 0.f;
#pragma unroll
    for (int j = 0; j < 8; ++j) {
      a += q0f[j] * (float)kr[w][0][j] + q0f[8 + j] * (float)kr[w][1][j];
      b += q1f[j] * (float)kr[w + 1][0][j] + q1f[8 + j] * (float)kr[w + 1][1][j];
    }
    d0[w] = a; d1[w] = b;
  }
#pragma unroll
  for (int off = 32; off >= 1; off >>= 1) {
#pragma unroll
    for (int w = 0; w < 5; ++w) {
      d0[w] += __shfl_xor(d0[w], off, 64);
      d1[w] += __shfl_xor(d1[w], off, 64);
    }
  }

  const float NEG = -__builtin_inff();
  float sc0[5], sc1[5];
#pragma unroll
  for (int w = 0; w < 5; ++w) {
    sc0[w] = val[w] ? d0[w] * (1.0f / 32.0f) : NEG;
    sc1[w] = val[w + 1] ? d1[w] * (1.0f / 32.0f) : NEG;
  }
  float m0_ = NEG, m1_ = NEG;
#pragma unroll
  for (int w = 0; w < 5; ++w) { m0_ = fmaxf(m0_, sc0[w]); m1_ = fmaxf(m1_, sc1[w]); }
  float e0[5], e1[5], su0 = 0.f, su1 = 0.f;
#pragma unroll
  for (int w = 0; w < 5; ++w) {
    e0[w] = __expf(sc0[w] - m0_); su0 += e0[w];
    e1[w] = __expf(sc1[w] - m1_); su1 += e1[w];
  }
  const float i0 = 1.0f / su0, i1 = 1.0f / su1;

  float of0[16], of1[16];
#pragma unroll
  for (int j = 0; j < 16; ++j) { of0[j] = 0.f; of1[j] = 0.f; }
#pragma unroll
  for (int w = 0; w < 5; ++w) {
    const float p0w = e0[w] * i0;
    const float p1w = e1[w] * i1;
#pragma unroll
    for (int j = 0; j < 8; ++j) {
      of0[j]     += p0w * (float)vr[w][0][j];
      of0[8 + j] += p0w * (float)vr[w][1][j];
      of1[j]     += p1w * (float)vr[w + 1][0][j];
      of1[8 + j] += p1w * (float)vr[w + 1][1][j];
    }
  }

  float* op0 = out + (size_t)p0 * 1024 + hoff;
  float* op1 = op0 + 1024;
#pragma unroll
  for (int j4 = 0; j4 < 4; ++j4) {
    f32x4 o0 = {of0[4 * j4], of0[4 * j4 + 1], of0[4 * j4 + 2], of0[4 * j4 + 3]};
    f32x4 o1 = {of1[4 * j4], of1[4 * j4 + 1], of1[4 * j4 + 2], of1[4 * j4 + 3]};
    *reinterpret_cast<f32x4*>(op0 + 4 * j4) = o0;
    *reinterpret_cast<f32x4*>(op1 + 4 * j4) = o1;
  }
}

extern "C" void kernel_launch(void* const* d_in, const int* in_sizes, int n_in,
                              void* d_out, int out_size, void* d_ws,
                              size_t ws_size, hipStream_t stream) {
  const float* x  = (const float*)d_in[0];
  const float* Wq = (const float*)d_in[1];
  const float* bq = (const float*)d_in[2];
  const float* Wk = (const float*)d_in[3];
  const float* bk = (const float*)d_in[4];
  const float* Wv = (const float*)d_in[5];
  const float* bv = (const float*)d_in[6];

  char* ws = (char*)d_ws;
  bf16* xb  = (bf16*)ws;                       // 16 MB: x as bf16
  bf16* Wt  = (bf16*)(ws + (size_t)16777216);  // 6 MB: [3072][1024] W^T bf16
  bf16* QKV = (bf16*)(ws + (size_t)23068672);  // 48 MB: fused [8192][3072]
  float* outf = (float*)d_out;

  prep_kernel<<<dim3(32, 32, 4), 256, 0, stream>>>(x, Wq, Wk, Wv, xb, Wt);
  qkv_gemm_kernel<<<dim3(24, 32), 512, 0, stream>>>(xb, Wt, bq, bk, bv, QKV);
  local_attn_kernel<<<1024, 256, 0, stream>>>(QKV, outf);
}